// Round 2
// baseline (195.783 us; speedup 1.0000x reference)
//
#include <hip/hip_runtime.h>

// InteractionNetwork B=4, N=256, D=128, L=3.
// Key algebraic rewrite: agg = (sum_j adj_ij * relu(xi_p_i + xj_p_j + eb1)) @ ew2
//                              + rowsum(adj)_i * eb2
// -> never materialize [B,N,N,D]; per-layer cost drops 8.8 GFLOP -> 0.3 GFLOP.

#define DD 128
#define NN 256
#define BB 4
#define BNR 1024  // B*N rows

// ---------------- layer-0 projection: xi_p = x@ew1[:D] + eb1 ; xj_p = x@ew1[D:]
__global__ __launch_bounds__(256) void kproj(
    const float* __restrict__ x,    // [BN,D]
    const float* __restrict__ w,    // [2D,D]
    const float* __restrict__ b1,   // [D]
    float* __restrict__ xi, float* __restrict__ xj)
{
  const int r0 = blockIdx.x * 8;
  const int t  = threadIdx.x;
  const int c  = t & 127;
  const int rg = t >> 7;
  __shared__ float xs[8][DD];
  ((float4*)xs)[t] = ((const float4*)(x + r0 * DD))[t];
  __syncthreads();

  float ai[4] = {0.f,0.f,0.f,0.f};
  float aj[4] = {0.f,0.f,0.f,0.f};
  const float* wi = w;
  const float* wj = w + DD * DD;
  for (int k = 0; k < DD; k += 4) {
    float wiv[4], wjv[4];
#pragma unroll
    for (int q = 0; q < 4; ++q) {
      wiv[q] = wi[(k + q) * DD + c];
      wjv[q] = wj[(k + q) * DD + c];
    }
#pragma unroll
    for (int i = 0; i < 4; ++i) {
      const float4 xv = *(const float4*)&xs[rg * 4 + i][k];
      ai[i] = fmaf(xv.x, wiv[0], ai[i]); ai[i] = fmaf(xv.y, wiv[1], ai[i]);
      ai[i] = fmaf(xv.z, wiv[2], ai[i]); ai[i] = fmaf(xv.w, wiv[3], ai[i]);
      aj[i] = fmaf(xv.x, wjv[0], aj[i]); aj[i] = fmaf(xv.y, wjv[1], aj[i]);
      aj[i] = fmaf(xv.z, wjv[2], aj[i]); aj[i] = fmaf(xv.w, wjv[3], aj[i]);
    }
  }
  const float bv = b1[c];
#pragma unroll
  for (int i = 0; i < 4; ++i) {
    const int r = r0 + rg * 4 + i;
    xi[r * DD + c] = ai[i] + bv;
    xj[r * DD + c] = aj[i];
  }
}

// ---------------- aggregation: Hagg[b,i,d] = sum_j adj[b,i,j]*relu(xi[b,i,d]+xj[b,j,d])
//                  rowsum[b,i] = sum_j adj[b,i,j]
__global__ __launch_bounds__(256) void kagg(
    const float* __restrict__ xi, const float* __restrict__ xj,
    const float* __restrict__ adj,   // [B,N,N]
    float* __restrict__ hagg, float* __restrict__ rowsum)
{
  const int b  = blockIdx.x >> 6;
  const int i0 = (blockIdx.x & 63) * 4;
  const int t  = threadIdx.x;
  const int d  = t & 127;
  const int jh = t >> 7;       // j-half handled by this thread
  __shared__ float adjs[4][NN];
  __shared__ float red[4][DD];

  ((float4*)adjs)[t] = ((const float4*)(adj + b * NN * NN + i0 * NN))[t];
  __syncthreads();

  float xiv[4];
#pragma unroll
  for (int i = 0; i < 4; ++i) xiv[i] = xi[(b * NN + i0 + i) * DD + d];

  float acc[4] = {0.f,0.f,0.f,0.f};
  const float* xjp = xj + (b * NN + jh * 128) * DD + d;
#pragma unroll 4
  for (int jj = 0; jj < 128; ++jj) {
    const float xsv = xjp[jj * DD];
    const int j = jh * 128 + jj;
#pragma unroll
    for (int i = 0; i < 4; ++i) {
      const float h = fmaxf(xiv[i] + xsv, 0.f);
      acc[i] = fmaf(adjs[i][j], h, acc[i]);
    }
  }

  if (jh == 1) {
#pragma unroll
    for (int i = 0; i < 4; ++i) red[i][d] = acc[i];
  }
  __syncthreads();
  if (jh == 0) {
#pragma unroll
    for (int i = 0; i < 4; ++i)
      hagg[(b * NN + i0 + i) * DD + d] = acc[i] + red[i][d];
  }

  // rowsum: wave w (0..3) reduces row i0+w
  const int w = t >> 6, lane = t & 63;
  float s = adjs[w][lane] + adjs[w][lane + 64] + adjs[w][lane + 128] + adjs[w][lane + 192];
  for (int off = 32; off; off >>= 1) s += __shfl_down(s, off);
  if (lane == 0) rowsum[b * NN + i0 + w] = s;
}

// ---------------- fused: agg = Hagg@ew2 + rowsum*eb2 ; node MLP ; residual ;
//                  and (if has_next) next layer's projection
__global__ __launch_bounds__(256) void kmlp(
    const float* __restrict__ xin, const float* __restrict__ hagg,
    const float* __restrict__ rowsum,
    const float* __restrict__ ew2, const float* __restrict__ eb2,
    const float* __restrict__ nw1, const float* __restrict__ nb1,
    const float* __restrict__ nw2, const float* __restrict__ nb2,
    float* __restrict__ xout,
    const float* __restrict__ ew1n, const float* __restrict__ eb1n,
    float* __restrict__ xi, float* __restrict__ xj, const int has_next)
{
  const int r0 = blockIdx.x * 8;
  const int t  = threadIdx.x;
  const int c  = t & 127;
  const int rg = t >> 7;
  __shared__ float xs[8][DD], hs[8][DD], ags[8][DD], ns[8][DD], os[8][DD];
  __shared__ float rs[8];

  ((float4*)xs)[t] = ((const float4*)(xin  + r0 * DD))[t];
  ((float4*)hs)[t] = ((const float4*)(hagg + r0 * DD))[t];
  if (t < 8) rs[t] = rowsum[r0 + t];
  __syncthreads();

  // ---- agg tile = Hagg_tile @ ew2 + rowsum*eb2
  {
    float acc[4] = {0.f,0.f,0.f,0.f};
    for (int k = 0; k < DD; k += 4) {
      float wv[4];
#pragma unroll
      for (int q = 0; q < 4; ++q) wv[q] = ew2[(k + q) * DD + c];
#pragma unroll
      for (int i = 0; i < 4; ++i) {
        const float4 h4 = *(const float4*)&hs[rg * 4 + i][k];
        acc[i] = fmaf(h4.x, wv[0], acc[i]); acc[i] = fmaf(h4.y, wv[1], acc[i]);
        acc[i] = fmaf(h4.z, wv[2], acc[i]); acc[i] = fmaf(h4.w, wv[3], acc[i]);
      }
    }
    const float eb2v = eb2[c];
#pragma unroll
    for (int i = 0; i < 4; ++i)
      ags[rg * 4 + i][c] = fmaf(rs[rg * 4 + i], eb2v, acc[i]);
  }
  __syncthreads();

  // ---- nh = relu(x@nw1a + agg@nw1b + nb1)
  {
    float acc[4] = {0.f,0.f,0.f,0.f};
    for (int k = 0; k < DD; k += 4) {
      float wa[4], wb[4];
#pragma unroll
      for (int q = 0; q < 4; ++q) {
        wa[q] = nw1[(k + q) * DD + c];
        wb[q] = nw1[(DD + k + q) * DD + c];
      }
#pragma unroll
      for (int i = 0; i < 4; ++i) {
        const float4 x4 = *(const float4*)&xs[rg * 4 + i][k];
        const float4 a4 = *(const float4*)&ags[rg * 4 + i][k];
        acc[i] = fmaf(x4.x, wa[0], acc[i]); acc[i] = fmaf(x4.y, wa[1], acc[i]);
        acc[i] = fmaf(x4.z, wa[2], acc[i]); acc[i] = fmaf(x4.w, wa[3], acc[i]);
        acc[i] = fmaf(a4.x, wb[0], acc[i]); acc[i] = fmaf(a4.y, wb[1], acc[i]);
        acc[i] = fmaf(a4.z, wb[2], acc[i]); acc[i] = fmaf(a4.w, wb[3], acc[i]);
      }
    }
    const float nb1v = nb1[c];
#pragma unroll
    for (int i = 0; i < 4; ++i)
      ns[rg * 4 + i][c] = fmaxf(acc[i] + nb1v, 0.f);
  }
  __syncthreads();

  // ---- upd = nh@nw2 + nb2 ; xout = xin + upd
  {
    float acc[4] = {0.f,0.f,0.f,0.f};
    for (int k = 0; k < DD; k += 4) {
      float wv[4];
#pragma unroll
      for (int q = 0; q < 4; ++q) wv[q] = nw2[(k + q) * DD + c];
#pragma unroll
      for (int i = 0; i < 4; ++i) {
        const float4 n4 = *(const float4*)&ns[rg * 4 + i][k];
        acc[i] = fmaf(n4.x, wv[0], acc[i]); acc[i] = fmaf(n4.y, wv[1], acc[i]);
        acc[i] = fmaf(n4.z, wv[2], acc[i]); acc[i] = fmaf(n4.w, wv[3], acc[i]);
      }
    }
    const float nb2v = nb2[c];
#pragma unroll
    for (int i = 0; i < 4; ++i) {
      const int r = rg * 4 + i;
      const float xo = xs[r][c] + acc[i] + nb2v;
      xout[(r0 + r) * DD + c] = xo;
      os[r][c] = xo;
    }
  }
  if (!has_next) return;
  __syncthreads();

  // ---- next layer projection from xout tile
  {
    float ai[4] = {0.f,0.f,0.f,0.f};
    float aj[4] = {0.f,0.f,0.f,0.f};
    const float* wi = ew1n;
    const float* wj = ew1n + DD * DD;
    for (int k = 0; k < DD; k += 4) {
      float wiv[4], wjv[4];
#pragma unroll
      for (int q = 0; q < 4; ++q) {
        wiv[q] = wi[(k + q) * DD + c];
        wjv[q] = wj[(k + q) * DD + c];
      }
#pragma unroll
      for (int i = 0; i < 4; ++i) {
        const float4 xv = *(const float4*)&os[rg * 4 + i][k];
        ai[i] = fmaf(xv.x, wiv[0], ai[i]); ai[i] = fmaf(xv.y, wiv[1], ai[i]);
        ai[i] = fmaf(xv.z, wiv[2], ai[i]); ai[i] = fmaf(xv.w, wiv[3], ai[i]);
        aj[i] = fmaf(xv.x, wjv[0], aj[i]); aj[i] = fmaf(xv.y, wjv[1], aj[i]);
        aj[i] = fmaf(xv.z, wjv[2], aj[i]); aj[i] = fmaf(xv.w, wjv[3], aj[i]);
      }
    }
    const float eb1v = eb1n[c];
#pragma unroll
    for (int i = 0; i < 4; ++i) {
      const int r = r0 + rg * 4 + i;
      xi[r * DD + c] = ai[i] + eb1v;
      xj[r * DD + c] = aj[i];
    }
  }
}

extern "C" void kernel_launch(void* const* d_in, const int* in_sizes, int n_in,
                              void* d_out, int out_size, void* d_ws, size_t ws_size,
                              hipStream_t stream) {
  const float* x0   = (const float*)d_in[0];
  const float* adj  = (const float*)d_in[1];
  const float* ew1  = (const float*)d_in[2];
  const float* eb1  = (const float*)d_in[3];
  const float* ew2  = (const float*)d_in[4];
  const float* eb2  = (const float*)d_in[5];
  const float* nw1  = (const float*)d_in[6];
  const float* nb1  = (const float*)d_in[7];
  const float* nw2  = (const float*)d_in[8];
  const float* nb2  = (const float*)d_in[9];
  float* out = (float*)d_out;
  float* ws  = (float*)d_ws;

  float* xA   = ws;
  float* xB   = ws + 131072;
  float* xi   = ws + 262144;
  float* xj   = ws + 393216;
  float* hg   = ws + 524288;
  float* rsum = ws + 655360;

  kproj<<<128, 256, 0, stream>>>(x0, ew1, eb1, xi, xj);

  const float* xins[3]  = {x0, xA, xB};
  float*       xouts[3] = {xA, xB, out};
  for (int l = 0; l < 3; ++l) {
    kagg<<<256, 256, 0, stream>>>(xi, xj, adj, hg, rsum);
    const int ln = (l + 1 < 3) ? (l + 1) : 0;  // dummy ptr for last layer (unused)
    kmlp<<<128, 256, 0, stream>>>(
        xins[l], hg, rsum,
        ew2 + l * DD * DD, eb2 + l * DD,
        nw1 + l * 2 * DD * DD, nb1 + l * DD,
        nw2 + l * DD * DD, nb2 + l * DD,
        xouts[l],
        ew1 + ln * 2 * DD * DD, eb1 + ln * DD,
        xi, xj, (l + 1 < 3) ? 1 : 0);
  }
}

// Round 3
// 149.042 us; speedup vs baseline: 1.3136x; 1.3136x over previous
//
#include <hip/hip_runtime.h>

// InteractionNetwork B=4, N=256, D=128, L=3.
// agg = (sum_j adj_ij * relu(xi_p_i + xj_p_j + eb1)) @ ew2 + rowsum(adj)_i * eb2
// R2 lesson: previous version latency-bound (VALUBusy 6%, occ 4.8%, 128 blocks).
// This version: kagg split 4-way over j (1024 blocks, partials summed in kmlp);
// kmlp/kproj split 4-way over k within 512-thread blocks (256 blocks each).

#define DD 128
#define NN 256

// ---------------- layer-0 projection: xi = x@ew1[:D]+eb1 ; xj = x@ew1[D:]
// grid 256, block 512: c = t&127, kq = t>>7; 4 rows per block.
__global__ __launch_bounds__(512) void kproj(
    const float* __restrict__ x, const float* __restrict__ w,
    const float* __restrict__ b1,
    float* __restrict__ xi, float* __restrict__ xj)
{
  const int r0 = blockIdx.x * 4;
  const int t = threadIdx.x, c = t & 127, kq = t >> 7;
  __shared__ float xs[4][DD];
  __shared__ float red[2][4][4][DD];  // [ij][row][kq][c]

  ((float*)xs)[t] = x[r0 * DD + t];
  __syncthreads();

  float ai[4] = {0.f,0.f,0.f,0.f};
  float aj[4] = {0.f,0.f,0.f,0.f};
  const int k0 = kq * 32;
#pragma unroll 8
  for (int kk = 0; kk < 32; ++kk) {
    const int k = k0 + kk;
    const float wiv = w[k * DD + c];
    const float wjv = w[(DD + k) * DD + c];
#pragma unroll
    for (int r = 0; r < 4; ++r) {
      const float xv = xs[r][k];
      ai[r] = fmaf(xv, wiv, ai[r]);
      aj[r] = fmaf(xv, wjv, aj[r]);
    }
  }
#pragma unroll
  for (int r = 0; r < 4; ++r) {
    red[0][r][kq][c] = ai[r];
    red[1][r][kq][c] = aj[r];
  }
  __syncthreads();
  // kq-group q finalizes row q (both outputs)
  {
    const int r = kq;
    const float s0 = red[0][r][0][c] + red[0][r][1][c] + red[0][r][2][c] + red[0][r][3][c];
    const float s1 = red[1][r][0][c] + red[1][r][1][c] + red[1][r][2][c] + red[1][r][3][c];
    xi[(r0 + r) * DD + c] = s0 + b1[c];
    xj[(r0 + r) * DD + c] = s1;
  }
}

// ---------------- aggregation partials over a 64-wide j-chunk
// grid 1024 = b(4) x ib(64) x jc(4); block 256: d = t&127, jh = t>>7.
// hp[jc] : [BN, D] partial relu-weighted sums ; rp[jc] : [BN] partial rowsums
__global__ __launch_bounds__(256) void kagg(
    const float* __restrict__ xi, const float* __restrict__ xj,
    const float* __restrict__ adj,
    float* __restrict__ hp, float* __restrict__ rp)
{
  const int bid = blockIdx.x;
  const int jc = bid & 3;
  const int ib = (bid >> 2) & 63;
  const int b  = bid >> 8;
  const int i0 = ib * 4;
  const int t = threadIdx.x, d = t & 127, jh = t >> 7;
  __shared__ float adjs[4][64];
  __shared__ float red[4][DD];

  adjs[t >> 6][t & 63] = adj[(b * NN + i0 + (t >> 6)) * NN + jc * 64 + (t & 63)];
  __syncthreads();

  float xiv[4];
#pragma unroll
  for (int r = 0; r < 4; ++r) xiv[r] = xi[(b * NN + i0 + r) * DD + d];

  float acc[4] = {0.f,0.f,0.f,0.f};
  const float* xjp = xj + (b * NN + jc * 64 + jh * 32) * DD + d;
#pragma unroll 8
  for (int jj = 0; jj < 32; ++jj) {
    const float xsv = xjp[jj * DD];
    const int j = jh * 32 + jj;
#pragma unroll
    for (int r = 0; r < 4; ++r) {
      const float h = fmaxf(xiv[r] + xsv, 0.f);
      acc[r] = fmaf(adjs[r][j], h, acc[r]);
    }
  }

  if (jh == 1) {
#pragma unroll
    for (int r = 0; r < 4; ++r) red[r][d] = acc[r];
  }
  __syncthreads();
  if (jh == 0) {
#pragma unroll
    for (int r = 0; r < 4; ++r)
      hp[jc * 131072 + (b * NN + i0 + r) * DD + d] = acc[r] + red[r][d];
  }

  // partial rowsum: wave w reduces its 64-wide adj row
  const int w = t >> 6, lane = t & 63;
  float s = adjs[w][lane];
  for (int off = 32; off; off >>= 1) s += __shfl_down(s, off);
  if (lane == 0) rp[jc * 1024 + b * NN + i0 + w] = s;
}

// ---------------- fused: agg = Hagg@ew2 + rowsum*eb2 ; node MLP ; residual ;
// next layer's projection. grid 256, block 512 (c x kq), 4 rows/block.
__global__ __launch_bounds__(512) void kmlp(
    const float* __restrict__ xin, const float* __restrict__ hp,
    const float* __restrict__ rp,
    const float* __restrict__ ew2, const float* __restrict__ eb2,
    const float* __restrict__ nw1, const float* __restrict__ nb1,
    const float* __restrict__ nw2, const float* __restrict__ nb2,
    float* __restrict__ xout,
    const float* __restrict__ ew1n, const float* __restrict__ eb1n,
    float* __restrict__ xi, float* __restrict__ xj, const int has_next)
{
  const int r0 = blockIdx.x * 4;
  const int t = threadIdx.x, c = t & 127, kq = t >> 7;
  const int k0 = kq * 32;
  __shared__ float xs[4][DD], hs[4][DD], ags[4][DD], ns[4][DD], os[4][DD];
  __shared__ float red[2][4][4][DD];
  __shared__ float rs[4];

  ((float*)xs)[t] = xin[r0 * DD + t];
  ((float*)hs)[t] = hp[r0 * DD + t] + hp[131072 + r0 * DD + t]
                  + hp[262144 + r0 * DD + t] + hp[393216 + r0 * DD + t];
  if (t < 4) rs[t] = rp[r0 + t] + rp[1024 + r0 + t] + rp[2048 + r0 + t] + rp[3072 + r0 + t];
  __syncthreads();

  // ---- phase 1: ags = hs@ew2 + rs*eb2
  {
    float acc[4] = {0.f,0.f,0.f,0.f};
#pragma unroll 8
    for (int kk = 0; kk < 32; ++kk) {
      const int k = k0 + kk;
      const float wv = ew2[k * DD + c];
#pragma unroll
      for (int r = 0; r < 4; ++r) acc[r] = fmaf(hs[r][k], wv, acc[r]);
    }
#pragma unroll
    for (int r = 0; r < 4; ++r) red[0][r][kq][c] = acc[r];
    __syncthreads();
    {
      const int r = kq;
      const float s = red[0][r][0][c] + red[0][r][1][c] + red[0][r][2][c] + red[0][r][3][c];
      ags[r][c] = fmaf(rs[r], eb2[c], s);
    }
    __syncthreads();
  }

  // ---- phase 2: ns = relu(xs@nw1a + ags@nw1b + nb1)
  {
    float acc[4] = {0.f,0.f,0.f,0.f};
#pragma unroll 8
    for (int kk = 0; kk < 32; ++kk) {
      const int k = k0 + kk;
      const float wa = nw1[k * DD + c];
      const float wb = nw1[(DD + k) * DD + c];
#pragma unroll
      for (int r = 0; r < 4; ++r) {
        acc[r] = fmaf(xs[r][k], wa, acc[r]);
        acc[r] = fmaf(ags[r][k], wb, acc[r]);
      }
    }
#pragma unroll
    for (int r = 0; r < 4; ++r) red[0][r][kq][c] = acc[r];
    __syncthreads();
    {
      const int r = kq;
      const float s = red[0][r][0][c] + red[0][r][1][c] + red[0][r][2][c] + red[0][r][3][c];
      ns[r][c] = fmaxf(s + nb1[c], 0.f);
    }
    __syncthreads();
  }

  // ---- phase 3: upd = ns@nw2 + nb2 ; xout = xin + upd
  {
    float acc[4] = {0.f,0.f,0.f,0.f};
#pragma unroll 8
    for (int kk = 0; kk < 32; ++kk) {
      const int k = k0 + kk;
      const float wv = nw2[k * DD + c];
#pragma unroll
      for (int r = 0; r < 4; ++r) acc[r] = fmaf(ns[r][k], wv, acc[r]);
    }
#pragma unroll
    for (int r = 0; r < 4; ++r) red[0][r][kq][c] = acc[r];
    __syncthreads();
    {
      const int r = kq;
      const float s = red[0][r][0][c] + red[0][r][1][c] + red[0][r][2][c] + red[0][r][3][c];
      const float xo = xs[r][c] + s + nb2[c];
      xout[(r0 + r) * DD + c] = xo;
      os[r][c] = xo;
    }
  }
  if (!has_next) return;
  __syncthreads();

  // ---- phase 4: next layer projection from os
  {
    float ai[4] = {0.f,0.f,0.f,0.f};
    float aj[4] = {0.f,0.f,0.f,0.f};
#pragma unroll 8
    for (int kk = 0; kk < 32; ++kk) {
      const int k = k0 + kk;
      const float wiv = ew1n[k * DD + c];
      const float wjv = ew1n[(DD + k) * DD + c];
#pragma unroll
      for (int r = 0; r < 4; ++r) {
        const float ov = os[r][k];
        ai[r] = fmaf(ov, wiv, ai[r]);
        aj[r] = fmaf(ov, wjv, aj[r]);
      }
    }
#pragma unroll
    for (int r = 0; r < 4; ++r) {
      red[0][r][kq][c] = ai[r];
      red[1][r][kq][c] = aj[r];
    }
    __syncthreads();
    {
      const int r = kq;
      const float s0 = red[0][r][0][c] + red[0][r][1][c] + red[0][r][2][c] + red[0][r][3][c];
      const float s1 = red[1][r][0][c] + red[1][r][1][c] + red[1][r][2][c] + red[1][r][3][c];
      xi[(r0 + r) * DD + c] = s0 + eb1n[c];
      xj[(r0 + r) * DD + c] = s1;
    }
  }
}

extern "C" void kernel_launch(void* const* d_in, const int* in_sizes, int n_in,
                              void* d_out, int out_size, void* d_ws, size_t ws_size,
                              hipStream_t stream) {
  const float* x0  = (const float*)d_in[0];
  const float* adj = (const float*)d_in[1];
  const float* ew1 = (const float*)d_in[2];
  const float* eb1 = (const float*)d_in[3];
  const float* ew2 = (const float*)d_in[4];
  const float* eb2 = (const float*)d_in[5];
  const float* nw1 = (const float*)d_in[6];
  const float* nb1 = (const float*)d_in[7];
  const float* nw2 = (const float*)d_in[8];
  const float* nb2 = (const float*)d_in[9];
  float* out = (float*)d_out;
  float* ws  = (float*)d_ws;

  float* xA = ws;                 // 131072
  float* xB = ws + 131072;
  float* xi = ws + 262144;
  float* xj = ws + 393216;
  float* hp = ws + 524288;        // 4 x 131072
  float* rp = ws + 1048576;       // 4 x 1024

  kproj<<<256, 512, 0, stream>>>(x0, ew1, eb1, xi, xj);

  const float* xins[3]  = {x0, xA, xB};
  float*       xouts[3] = {xA, xB, out};
  for (int l = 0; l < 3; ++l) {
    kagg<<<1024, 256, 0, stream>>>(xi, xj, adj, hp, rp);
    const int ln = (l + 1 < 3) ? (l + 1) : 0;  // dummy for last layer (unused)
    kmlp<<<256, 512, 0, stream>>>(
        xins[l], hp, rp,
        ew2 + l * DD * DD, eb2 + l * DD,
        nw1 + l * 2 * DD * DD, nb1 + l * DD,
        nw2 + l * DD * DD, nb2 + l * DD,
        xouts[l],
        ew1 + ln * 2 * DD * DD, eb1 + ln * DD,
        xi, xj, (l + 1 < 3) ? 1 : 0);
  }
}

// Round 4
// 145.549 us; speedup vs baseline: 1.3451x; 1.0240x over previous
//
#include <hip/hip_runtime.h>

// InteractionNetwork B=4, N=256, D=128, L=3.
// agg = (sum_j adj_ij * relu(xi_p_i + xj_p_j + eb1)) @ ew2 + rowsum(adj)_i * eb2
// R3 lesson: still latency-bound (occ ~5%, VALUBusy ~6%). This round: occupancy.
// kagg: 2048 blocks (8-way j-split partials). kmlp: 512 blocks, 2 rows, merged
// phase A, VGPR-capped for >=4 waves/SIMD. kproj: 1024 blocks.

#define DD 128
#define NN 256

// ---------------- kproj: 1 row/block; grid 1024, block 512 (c=t&127, kq=t>>7)
__global__ __launch_bounds__(512, 4) void kproj(
    const float* __restrict__ x, const float* __restrict__ w,
    const float* __restrict__ b1,
    float* __restrict__ xi, float* __restrict__ xj)
{
  const int r = blockIdx.x;
  const int t = threadIdx.x, c = t & 127, kq = t >> 7;
  __shared__ float xs[DD];
  __shared__ float red[2][4][DD];
  if (t < DD) xs[t] = x[r * DD + t];
  __syncthreads();
  float ai = 0.f, aj = 0.f;
  const int k0 = kq * 32;
#pragma unroll 8
  for (int kk = 0; kk < 32; ++kk) {
    const int k = k0 + kk;
    const float xv = xs[k];
    ai = fmaf(xv, w[k * DD + c], ai);
    aj = fmaf(xv, w[(DD + k) * DD + c], aj);
  }
  red[0][kq][c] = ai;
  red[1][kq][c] = aj;
  __syncthreads();
  if (kq == 0)
    xi[r * DD + c] = red[0][0][c] + red[0][1][c] + red[0][2][c] + red[0][3][c] + b1[c];
  else if (kq == 1)
    xj[r * DD + c] = red[1][0][c] + red[1][1][c] + red[1][2][c] + red[1][3][c];
}

// ---------------- kagg: partials over 32-wide j-chunks
// grid 2048 = b(4) x ib(64) x jc(8); block 256: d=t&127, jh=t>>7 (16 j's each).
__global__ __launch_bounds__(256, 4) void kagg(
    const float* __restrict__ xi, const float* __restrict__ xj,
    const float* __restrict__ adj,
    float* __restrict__ hp, float* __restrict__ rp)
{
  const int bid = blockIdx.x;
  const int jc = bid & 7;
  const int ib = (bid >> 3) & 63;
  const int b  = bid >> 9;
  const int i0 = ib * 4;
  const int t = threadIdx.x, d = t & 127, jh = t >> 7;
  __shared__ float adjs[4][32];
  __shared__ float red[4][DD];

  if (t < 128) adjs[t >> 5][t & 31] = adj[(b * NN + i0 + (t >> 5)) * NN + jc * 32 + (t & 31)];
  __syncthreads();

  float xiv[4];
#pragma unroll
  for (int r = 0; r < 4; ++r) xiv[r] = xi[(b * NN + i0 + r) * DD + d];

  float acc[4] = {0.f, 0.f, 0.f, 0.f};
  const float* xjp = xj + (b * NN + jc * 32 + jh * 16) * DD + d;
#pragma unroll
  for (int jj = 0; jj < 16; ++jj) {
    const float xsv = xjp[jj * DD];
    const int j = jh * 16 + jj;
#pragma unroll
    for (int r = 0; r < 4; ++r) {
      const float h = fmaxf(xiv[r] + xsv, 0.f);
      acc[r] = fmaf(adjs[r][j], h, acc[r]);
    }
  }

  if (jh == 1) {
#pragma unroll
    for (int r = 0; r < 4; ++r) red[r][d] = acc[r];
  }
  __syncthreads();
  if (jh == 0) {
#pragma unroll
    for (int r = 0; r < 4; ++r)
      hp[jc * 131072 + (b * NN + i0 + r) * DD + d] = acc[r] + red[r][d];
  }

  // partial rowsum over this 32-j chunk: wave w reduces row w
  const int w = t >> 6, lane = t & 63;
  float s = (lane < 32) ? adjs[w][lane] : 0.f;
  for (int off = 32; off; off >>= 1) s += __shfl_down(s, off);
  if (lane == 0) rp[jc * 1024 + b * NN + i0 + w] = s;
}

// ---------------- kmlp: 2 rows/block; grid 512, block 512 (c=t&127, kq=t>>7)
__global__ __launch_bounds__(512, 4) void kmlp(
    const float* __restrict__ xin, const float* __restrict__ hp,
    const float* __restrict__ rp,
    const float* __restrict__ ew2, const float* __restrict__ eb2,
    const float* __restrict__ nw1, const float* __restrict__ nb1,
    const float* __restrict__ nw2, const float* __restrict__ nb2,
    float* __restrict__ xout,
    const float* __restrict__ ew1n, const float* __restrict__ eb1n,
    float* __restrict__ xi, float* __restrict__ xj, const int has_next)
{
  const int r0 = blockIdx.x * 2;
  const int t = threadIdx.x, c = t & 127, kq = t >> 7;
  const int k0 = kq * 32;
  __shared__ float xs[2][DD], hsp[2][2 * DD], ags[2][DD], ns[2][DD], os[2][DD];
  __shared__ float red[2][2][4][DD];  // [stream][row][kq][c]
  __shared__ float rs[2];

  // stage: hp partial-sums (8 -> 2 halves), xs, rs
  {
    const int cc = t & 255, hh = t >> 8;
    float s = 0.f;
#pragma unroll
    for (int p = 0; p < 4; ++p) s += hp[(hh * 4 + p) * 131072 + r0 * DD + cc];
    hsp[hh][cc] = s;
    if (hh == 1) ((float*)xs)[cc] = xin[r0 * DD + cc];
    if (t < 2) {
      float rsv = 0.f;
#pragma unroll
      for (int p = 0; p < 8; ++p) rsv += rp[p * 1024 + r0 + t];
      rs[t] = rsv;
    }
  }
  __syncthreads();

  // Phase A: a1 = hs@ew2 (-> ags) merged with a2 = xs@nw1a (kept for B)
  float a2[2];
  {
    float a1[2] = {0.f, 0.f};
    a2[0] = 0.f; a2[1] = 0.f;
#pragma unroll 8
    for (int kk = 0; kk < 32; ++kk) {
      const int k = k0 + kk;
      const float w2v = ew2[k * DD + c];
      const float wav = nw1[k * DD + c];
#pragma unroll
      for (int r = 0; r < 2; ++r) {
        const float hv = hsp[0][r * DD + k] + hsp[1][r * DD + k];
        a1[r] = fmaf(hv, w2v, a1[r]);
        a2[r] = fmaf(xs[r][k], wav, a2[r]);
      }
    }
#pragma unroll
    for (int r = 0; r < 2; ++r) red[0][r][kq][c] = a1[r];
  }
  __syncthreads();
  if (kq < 2) {
    const int r = kq;
    const float s = red[0][r][0][c] + red[0][r][1][c] + red[0][r][2][c] + red[0][r][3][c];
    ags[r][c] = fmaf(rs[r], eb2[c], s);
  }
  __syncthreads();

  // Phase B: a3 = ags@nw1b ; ns = relu(reduce(a2+a3) + nb1)
  {
    float a3[2] = {0.f, 0.f};
#pragma unroll 8
    for (int kk = 0; kk < 32; ++kk) {
      const int k = k0 + kk;
      const float wbv = nw1[(DD + k) * DD + c];
#pragma unroll
      for (int r = 0; r < 2; ++r) a3[r] = fmaf(ags[r][k], wbv, a3[r]);
    }
#pragma unroll
    for (int r = 0; r < 2; ++r) red[0][r][kq][c] = a2[r] + a3[r];
  }
  __syncthreads();
  if (kq < 2) {
    const int r = kq;
    const float s = red[0][r][0][c] + red[0][r][1][c] + red[0][r][2][c] + red[0][r][3][c];
    ns[r][c] = fmaxf(s + nb1[c], 0.f);
  }
  __syncthreads();

  // Phase C: upd = ns@nw2 ; os = xs + upd + nb2 ; write xout
  {
    float a4[2] = {0.f, 0.f};
#pragma unroll 8
    for (int kk = 0; kk < 32; ++kk) {
      const int k = k0 + kk;
      const float wv = nw2[k * DD + c];
#pragma unroll
      for (int r = 0; r < 2; ++r) a4[r] = fmaf(ns[r][k], wv, a4[r]);
    }
#pragma unroll
    for (int r = 0; r < 2; ++r) red[0][r][kq][c] = a4[r];
  }
  __syncthreads();
  if (kq < 2) {
    const int r = kq;
    const float s = red[0][r][0][c] + red[0][r][1][c] + red[0][r][2][c] + red[0][r][3][c];
    const float xo = xs[r][c] + s + nb2[c];
    xout[(r0 + r) * DD + c] = xo;
    os[r][c] = xo;
  }
  if (!has_next) return;
  __syncthreads();

  // Phase D: next-layer projection from os
  {
    float ai[2] = {0.f, 0.f}, aj[2] = {0.f, 0.f};
#pragma unroll 8
    for (int kk = 0; kk < 32; ++kk) {
      const int k = k0 + kk;
      const float wiv = ew1n[k * DD + c];
      const float wjv = ew1n[(DD + k) * DD + c];
#pragma unroll
      for (int r = 0; r < 2; ++r) {
        const float ov = os[r][k];
        ai[r] = fmaf(ov, wiv, ai[r]);
        aj[r] = fmaf(ov, wjv, aj[r]);
      }
    }
#pragma unroll
    for (int r = 0; r < 2; ++r) {
      red[0][r][kq][c] = ai[r];
      red[1][r][kq][c] = aj[r];
    }
  }
  __syncthreads();
  {
    // 4 finalizer groups: kq = stream*2 + row
    const int st = kq >> 1, r = kq & 1;
    const float s = red[st][r][0][c] + red[st][r][1][c] + red[st][r][2][c] + red[st][r][3][c];
    if (st == 0) xi[(r0 + r) * DD + c] = s + eb1n[c];
    else         xj[(r0 + r) * DD + c] = s;
  }
}

extern "C" void kernel_launch(void* const* d_in, const int* in_sizes, int n_in,
                              void* d_out, int out_size, void* d_ws, size_t ws_size,
                              hipStream_t stream) {
  const float* x0  = (const float*)d_in[0];
  const float* adj = (const float*)d_in[1];
  const float* ew1 = (const float*)d_in[2];
  const float* eb1 = (const float*)d_in[3];
  const float* ew2 = (const float*)d_in[4];
  const float* eb2 = (const float*)d_in[5];
  const float* nw1 = (const float*)d_in[6];
  const float* nb1 = (const float*)d_in[7];
  const float* nw2 = (const float*)d_in[8];
  const float* nb2 = (const float*)d_in[9];
  float* out = (float*)d_out;
  float* ws  = (float*)d_ws;

  float* xA = ws;                 // 131072
  float* xB = ws + 131072;
  float* xi = ws + 262144;
  float* xj = ws + 393216;
  float* hp = ws + 524288;        // 8 x 131072
  float* rp = ws + 1572864;       // 8 x 1024

  kproj<<<1024, 512, 0, stream>>>(x0, ew1, eb1, xi, xj);

  const float* xins[3]  = {x0, xA, xB};
  float*       xouts[3] = {xA, xB, out};
  for (int l = 0; l < 3; ++l) {
    kagg<<<2048, 256, 0, stream>>>(xi, xj, adj, hp, rp);
    const int ln = (l + 1 < 3) ? (l + 1) : 0;  // dummy for last layer (unused)
    kmlp<<<512, 512, 0, stream>>>(
        xins[l], hp, rp,
        ew2 + l * DD * DD, eb2 + l * DD,
        nw1 + l * 2 * DD * DD, nb1 + l * DD,
        nw2 + l * DD * DD, nb2 + l * DD,
        xouts[l],
        ew1 + ln * 2 * DD * DD, eb1 + ln * DD,
        xi, xj, (l + 1 < 3) ? 1 : 0);
  }
}